// Round 1
// baseline (6077.925 us; speedup 1.0000x reference)
//
#include <hip/hip_runtime.h>
#include <math.h>

#define D_MODEL 2048
#define NH 16
#define Q_LORA 1536
#define KV_LORA 512
#define DN 128
#define DR 64
#define DV 128
#define BB 2
#define SS 2048
#define NROWS (BB*SS)
#define LN_EPS 1e-5f

// ---------------------------------------------------------------------------
// Generic tiled GEMM: C = A @ B^T
// A: M x K (lda), B: N x K (ldb), C: M x N (ldc). blockIdx.z batches B and C.
// Requires M%64==0, N%64==0, K%16==0 (true for all shapes here).
// ---------------------------------------------------------------------------
__global__ __launch_bounds__(256)
void gemm_abt(const float* __restrict__ A, const float* __restrict__ B,
              float* __restrict__ C, int M, int N, int K,
              int lda, int ldb, int ldc, long sB, long sC)
{
    B += (long)blockIdx.z * sB;
    C += (long)blockIdx.z * sC;
    __shared__ __align__(16) float As[64][17];
    __shared__ __align__(16) float Bs[64][17];
    int tid = threadIdx.x;
    int tx = tid & 15, ty = tid >> 4;
    int m0 = blockIdx.y * 64, n0 = blockIdx.x * 64;
    float acc[4][4] = {};
    for (int k0 = 0; k0 < K; k0 += 16) {
        int r = tid >> 2, c4 = (tid & 3) * 4;
        float4 va = *(const float4*)(A + (long)(m0 + r) * lda + k0 + c4);
        float4 vb = *(const float4*)(B + (long)(n0 + r) * ldb + k0 + c4);
        As[r][c4+0]=va.x; As[r][c4+1]=va.y; As[r][c4+2]=va.z; As[r][c4+3]=va.w;
        Bs[r][c4+0]=vb.x; Bs[r][c4+1]=vb.y; Bs[r][c4+2]=vb.z; Bs[r][c4+3]=vb.w;
        __syncthreads();
        #pragma unroll
        for (int kk = 0; kk < 16; ++kk) {
            float a[4], b[4];
            #pragma unroll
            for (int i=0;i<4;i++) a[i] = As[ty*4+i][kk];
            #pragma unroll
            for (int j=0;j<4;j++) b[j] = Bs[tx*4+j][kk];
            #pragma unroll
            for (int i=0;i<4;i++)
                #pragma unroll
                for (int j=0;j<4;j++)
                    acc[i][j] += a[i]*b[j];
        }
        __syncthreads();
    }
    #pragma unroll
    for (int i=0;i<4;i++){
        long m = m0 + ty*4 + i;
        #pragma unroll
        for (int j=0;j<4;j++){
            C[m*ldc + n0 + tx*4 + j] = acc[i][j];
        }
    }
}

// ---------------------------------------------------------------------------
// Row LayerNorm: one block per row.
// ---------------------------------------------------------------------------
__global__ __launch_bounds__(256)
void ln_rows(const float* __restrict__ in, float* __restrict__ out,
             const float* __restrict__ g, const float* __restrict__ b,
             int n, int ld_in, int ld_out)
{
    long row = blockIdx.x;
    const float* x = in + row * ld_in;
    float* y = out + row * ld_out;
    int tid = threadIdx.x;
    float s = 0.f, ss = 0.f;
    for (int i = tid; i < n; i += 256) { float v = x[i]; s += v; ss += v*v; }
    #pragma unroll
    for (int off = 32; off > 0; off >>= 1) {
        s  += __shfl_xor(s, off);
        ss += __shfl_xor(ss, off);
    }
    __shared__ float sred[4], ssred[4];
    int wid = tid >> 6, lane = tid & 63;
    if (lane == 0) { sred[wid] = s; ssred[wid] = ss; }
    __syncthreads();
    s  = sred[0]+sred[1]+sred[2]+sred[3];
    ss = ssred[0]+ssred[1]+ssred[2]+ssred[3];
    float mu  = s / n;
    float var = ss / n - mu*mu;
    float r = 1.0f / sqrtf(var + LN_EPS);
    for (int i = tid; i < n; i += 256) {
        y[i] = (x[i]-mu)*r*g[i] + b[i];
    }
}

// ---------------------------------------------------------------------------
// RoPE, q path: in-place on q_rope (NROWS, NH, 64). One thread per (row,h,i).
// ---------------------------------------------------------------------------
__global__ __launch_bounds__(256)
void rope_q_kernel(float* __restrict__ qr, const int* __restrict__ pos)
{
    long idx = (long)blockIdx.x * 256 + threadIdx.x;
    if (idx >= (long)NROWS * NH * 32) return;
    int i = (int)(idx & 31);
    long rowh = idx >> 5;            // row*NH + h
    int row = (int)(rowh >> 4);
    int s = row & (SS - 1);
    double ang = (double)pos[s] * exp(-(double)i * 0.28782313662425572); // ln(1e4)/32
    float c = (float)cos(ang), sn = (float)sin(ang);
    float* p = qr + rowh * 64;
    float x1 = p[i], x2 = p[i+32];
    p[i]    = x1*c - x2*sn;
    p[i+32] = x1*sn + x2*c;
}

// ---------------------------------------------------------------------------
// RoPE, k path: kv_mixed[:,512:576] -> k_rope (NROWS, 64).
// ---------------------------------------------------------------------------
__global__ __launch_bounds__(256)
void rope_k_kernel(const float* __restrict__ kvm, float* __restrict__ krope,
                   const int* __restrict__ pos)
{
    int idx = blockIdx.x * 256 + threadIdx.x;
    if (idx >= NROWS * 32) return;
    int i = idx & 31;
    int row = idx >> 5;
    int s = row & (SS - 1);
    double ang = (double)pos[s] * exp(-(double)i * 0.28782313662425572);
    float c = (float)cos(ang), sn = (float)sin(ang);
    const float* p = kvm + (long)row * (KV_LORA + DR) + KV_LORA;
    float x1 = p[i], x2 = p[i+32];
    krope[(long)row*64 + i]      = x1*c - x2*sn;
    krope[(long)row*64 + i + 32] = x1*sn + x2*c;
}

// ---------------------------------------------------------------------------
// Flash attention, fp32 vector. head_dim_qk=192, head_dim_v=128, no mask.
// Grid: (S/TQ, B*NH). Block 256. TQ=64 q rows, TK=32 k rows per tile.
// Thread (tx=tid&15, ty=tid>>4): 4 q-rows x 8 v-cols accumulators,
// v = tx + 16*vi (conflict-free LDS column access).
// ---------------------------------------------------------------------------
#define TQ 64
#define TK 32
#define DQK 192
#define ATT_SCALE 0.07216878364870322f  // 1/sqrt(192)

__global__ __launch_bounds__(256)
void flash_attn(const float* __restrict__ q_nope, const float* __restrict__ q_rope,
                const float* __restrict__ k_exp,  const float* __restrict__ k_rope,
                const float* __restrict__ v_exp,  float* __restrict__ attn_v)
{
    int q0 = blockIdx.x * TQ;
    int bh = blockIdx.y;
    int b = bh >> 4, h = bh & 15;
    __shared__ __align__(16) float Qs[TQ][DQK];   // 49.2 KB
    __shared__ __align__(16) float Ks[TK][196];   // 25.1 KB (padded, 16B-aligned rows)
    __shared__ __align__(16) float Vs[TK][DV];    // 16.4 KB
    __shared__ __align__(16) float Ss[TQ][36];    //  9.2 KB
    __shared__ float mM[TQ], mL[TQ], mAl[TQ];
    int tid = threadIdx.x;
    int tx = tid & 15, ty = tid >> 4;
    long rowbase = (long)b * SS + q0;

    for (int idx = tid; idx < TQ*DN; idx += 256) {
        int r = idx >> 7, c = idx & 127;
        Qs[r][c] = q_nope[((rowbase + r)*NH + h)*DN + c];
    }
    for (int idx = tid; idx < TQ*DR; idx += 256) {
        int r = idx >> 6, c = idx & 63;
        Qs[r][DN + c] = q_rope[((rowbase + r)*NH + h)*DR + c];
    }
    if (tid < TQ) { mM[tid] = -INFINITY; mL[tid] = 0.f; }
    float acc[4][8] = {};
    __syncthreads();

    for (int k0 = 0; k0 < SS; k0 += TK) {
        long krow = (long)b * SS + k0;
        for (int idx = tid; idx < TK*DN; idx += 256) {
            int r = idx >> 7, c = idx & 127;
            Ks[r][c] = k_exp[((krow + r)*NH + h)*DN + c];
            Vs[r][c] = v_exp[((krow + r)*NH + h)*DV + c];
        }
        for (int idx = tid; idx < TK*DR; idx += 256) {
            int r = idx >> 6, c = idx & 63;
            Ks[r][DN + c] = k_rope[(krow + r)*DR + c];
        }
        __syncthreads();

        // scores: 4 q-rows x 2 k-cols per thread, float4 along the 192 dim
        float sc[4][2] = {};
        #pragma unroll 4
        for (int kk = 0; kk < DQK; kk += 4) {
            float4 a[4], bv[2];
            #pragma unroll
            for (int i=0;i<4;i++) a[i] = *(const float4*)&Qs[ty*4+i][kk];
            #pragma unroll
            for (int j=0;j<2;j++) bv[j] = *(const float4*)&Ks[tx*2+j][kk];
            #pragma unroll
            for (int i=0;i<4;i++)
                #pragma unroll
                for (int j=0;j<2;j++)
                    sc[i][j] += a[i].x*bv[j].x + a[i].y*bv[j].y
                              + a[i].z*bv[j].z + a[i].w*bv[j].w;
        }
        #pragma unroll
        for (int i=0;i<4;i++)
            #pragma unroll
            for (int j=0;j<2;j++)
                Ss[ty*4+i][tx*2+j] = sc[i][j] * ATT_SCALE;
        __syncthreads();

        // online softmax per q row (64 threads)
        if (tid < TQ) {
            float m_old = mM[tid];
            float mx = m_old;
            #pragma unroll 8
            for (int j=0;j<TK;j++) mx = fmaxf(mx, Ss[tid][j]);
            float alpha = expf(m_old - mx);
            float sum = 0.f;
            #pragma unroll 8
            for (int j=0;j<TK;j++) {
                float p = expf(Ss[tid][j] - mx);
                Ss[tid][j] = p;
                sum += p;
            }
            mM[tid] = mx;
            mL[tid] = mL[tid]*alpha + sum;
            mAl[tid] = alpha;
        }
        __syncthreads();

        // PV accumulate
        #pragma unroll
        for (int i=0;i<4;i++) {
            int qi = ty*4+i;
            float al = mAl[qi];
            #pragma unroll
            for (int vi=0;vi<8;vi++) acc[i][vi] *= al;
            for (int j=0;j<TK;j++) {
                float p = Ss[qi][j];
                #pragma unroll
                for (int vi=0;vi<8;vi++)
                    acc[i][vi] += p * Vs[j][tx + vi*16];
            }
        }
        __syncthreads();
    }

    #pragma unroll
    for (int i=0;i<4;i++) {
        int qi = ty*4+i;
        float inv = 1.0f / mL[qi];
        long obase = ((rowbase + qi)*NH + h)*DV;
        #pragma unroll
        for (int vi=0;vi<8;vi++)
            attn_v[obase + tx + vi*16] = acc[i][vi] * inv;
    }
}

// ---------------------------------------------------------------------------

extern "C" void kernel_launch(void* const* d_in, const int* in_sizes, int n_in,
                              void* d_out, int out_size, void* d_ws, size_t ws_size,
                              hipStream_t stream) {
    const float* hs       = (const float*)d_in[0];
    const float* w_qa     = (const float*)d_in[1];
    const float* ln_qa_g  = (const float*)d_in[2];
    const float* ln_qa_b  = (const float*)d_in[3];
    const float* w_qb     = (const float*)d_in[4];
    const float* w_qrope  = (const float*)d_in[5];
    const float* w_kva    = (const float*)d_in[6];
    const float* ln_kva_g = (const float*)d_in[7];
    const float* ln_kva_b = (const float*)d_in[8];
    const float* w_kvb    = (const float*)d_in[9];
    const float* w_o      = (const float*)d_in[10];
    const int*   pos      = (const int*)d_in[11];
    float* out = (float*)d_out;

    float* ws      = (float*)d_ws;
    float* q_lat   = ws;                      // 4096*1536 (q_mixed, LN in-place)
    float* q_nope  = q_lat  + (long)NROWS*Q_LORA;
    float* q_rope  = q_nope + (long)NROWS*NH*DN;
    float* kv_mix  = q_rope + (long)NROWS*NH*DR;
    float* kv_lat  = kv_mix + (long)NROWS*(KV_LORA+DR);
    float* k_rope  = kv_lat + (long)NROWS*KV_LORA;
    float* k_exp   = k_rope + (long)NROWS*DR;
    float* v_exp   = k_exp  + (long)NROWS*NH*DN;
    float* attn_v  = v_exp  + (long)NROWS*NH*DV;
    // total: 4096*11904 floats ≈ 195 MB

    dim3 blk(256);

    // 1. q_mixed = hs @ w_qa^T   (4096 x 1536, K=2048)
    gemm_abt<<<dim3(Q_LORA/64, NROWS/64, 1), blk, 0, stream>>>(
        hs, w_qa, q_lat, NROWS, Q_LORA, D_MODEL, D_MODEL, D_MODEL, Q_LORA, 0, 0);
    // 2. LN (in place)
    ln_rows<<<dim3(NROWS), blk, 0, stream>>>(q_lat, q_lat, ln_qa_g, ln_qa_b,
                                             Q_LORA, Q_LORA, Q_LORA);
    // 3. q_nope = q_lat @ w_qb^T  (4096 x 2048, K=1536)
    gemm_abt<<<dim3((NH*DN)/64, NROWS/64, 1), blk, 0, stream>>>(
        q_lat, w_qb, q_nope, NROWS, NH*DN, Q_LORA, Q_LORA, Q_LORA, NH*DN, 0, 0);
    // 4. q_rope = q_lat @ w_qrope^T (4096 x 1024, K=1536)
    gemm_abt<<<dim3((NH*DR)/64, NROWS/64, 1), blk, 0, stream>>>(
        q_lat, w_qrope, q_rope, NROWS, NH*DR, Q_LORA, Q_LORA, Q_LORA, NH*DR, 0, 0);
    // 5. kv_mixed = hs @ w_kva^T (4096 x 576, K=2048)
    gemm_abt<<<dim3((KV_LORA+DR)/64, NROWS/64, 1), blk, 0, stream>>>(
        hs, w_kva, kv_mix, NROWS, KV_LORA+DR, D_MODEL, D_MODEL, D_MODEL, KV_LORA+DR, 0, 0);
    // 6. kv_latent = LN(kv_mixed[:, :512])
    ln_rows<<<dim3(NROWS), blk, 0, stream>>>(kv_mix, kv_lat, ln_kva_g, ln_kva_b,
                                             KV_LORA, KV_LORA+DR, KV_LORA);
    // 7. RoPE q (in place)
    rope_q_kernel<<<dim3((NROWS*NH*32)/256), blk, 0, stream>>>(q_rope, pos);
    // 8. RoPE k -> k_rope
    rope_k_kernel<<<dim3((NROWS*32)/256), blk, 0, stream>>>(kv_mix, k_rope, pos);
    // 9. k_exp[h] = kv_lat @ k_up[h]^T  (batched over h)
    gemm_abt<<<dim3(DN/64, NROWS/64, NH), blk, 0, stream>>>(
        kv_lat, w_kvb, k_exp, NROWS, DN, KV_LORA,
        KV_LORA, KV_LORA, NH*DN, (long)DN*KV_LORA, (long)DN);
    // 10. v_exp[h] = kv_lat @ v_up[h]^T (batched over h)
    gemm_abt<<<dim3(DV/64, NROWS/64, NH), blk, 0, stream>>>(
        kv_lat, w_kvb + (long)NH*DN*KV_LORA, v_exp, NROWS, DV, KV_LORA,
        KV_LORA, KV_LORA, NH*DV, (long)DV*KV_LORA, (long)DV);
    // 11. flash attention -> attn_v (4096, 16, 128)
    flash_attn<<<dim3(SS/TQ, BB*NH), blk, 0, stream>>>(
        q_nope, q_rope, k_exp, k_rope, v_exp, attn_v);
    // 12. out = attn_v @ w_o^T (4096 x 2048, K=2048)
    gemm_abt<<<dim3(D_MODEL/64, NROWS/64, 1), blk, 0, stream>>>(
        attn_v, w_o, out, NROWS, D_MODEL, NH*DV, NH*DV, NH*DV, D_MODEL, 0, 0);
}

// Round 2
// 810.442 us; speedup vs baseline: 7.4995x; 7.4995x over previous
//
#include <hip/hip_runtime.h>
#include <math.h>

#define D_MODEL 2048
#define NH 16
#define Q_LORA 1536
#define KV_LORA 512
#define DN 128
#define DR 64
#define DV 128
#define BB 2
#define SS 2048
#define NROWS (BB*SS)
#define LN_EPS 1e-5f

typedef __attribute__((ext_vector_type(8))) short short8;
typedef __attribute__((ext_vector_type(4))) float f32x4;

__device__ __forceinline__ ushort f2bf(float f) {
    unsigned int u = __float_as_uint(f);
    u = u + 0x7fffu + ((u >> 16) & 1u);   // round-to-nearest-even
    return (ushort)(u >> 16);
}

// ---------------------------------------------------------------------------
// fp32 -> bf16 converters
// ---------------------------------------------------------------------------
__global__ __launch_bounds__(256)
void cvt_bf16(const float* __restrict__ in, ushort* __restrict__ out, long n4)
{
    long i = (long)blockIdx.x * 256 + threadIdx.x;
    if (i >= n4) return;
    float4 v = ((const float4*)in)[i];
    ushort4 o;
    o.x = f2bf(v.x); o.y = f2bf(v.y); o.z = f2bf(v.z); o.w = f2bf(v.w);
    ((ushort4*)out)[i] = o;
}

// w_kva (576 x 2048) -> bf16 padded to 640 rows (zero fill)
__global__ __launch_bounds__(256)
void cvt_pad_kva(const float* __restrict__ in, ushort* __restrict__ out)
{
    int i = blockIdx.x * 256 + threadIdx.x;   // one per 4 elements of 640x2048
    if (i >= 640 * 2048 / 4) return;
    int e = i * 4;
    int row = e >> 11, col = e & 2047;
    ushort4 o;
    if (row < 576) {
        float4 v = *(const float4*)(in + (long)row * 2048 + col);
        o.x = f2bf(v.x); o.y = f2bf(v.y); o.z = f2bf(v.z); o.w = f2bf(v.w);
    } else {
        o.x = 0; o.y = 0; o.z = 0; o.w = 0;
    }
    *(ushort4*)(out + (long)row * 2048 + col) = o;
}

// ---------------------------------------------------------------------------
// bf16 MFMA GEMM: C = A @ B^T.  A:[M][K] bf16, B:[N][K] bf16 (z-batched).
// 128x128 tile, BK=32, 256 threads (4 waves 2x2), global_load_lds staging.
// M%128==0, N%128==0, K%32==0 (holds for all shapes here).
// OUT_MODE: 0 = fp32 store, 1 = bf16 store, 2 = bf16 transposed store.
// ---------------------------------------------------------------------------
#define GLL16(g, l) \
    __builtin_amdgcn_global_load_lds((const __attribute__((address_space(1))) void*)(g), \
                                     (__attribute__((address_space(3))) void*)(l), 16, 0, 0)

template<int OUT_MODE>
__global__ __launch_bounds__(256)
void gemm_bf16(const ushort* __restrict__ A, const ushort* __restrict__ B,
               void* __restrict__ Cv, int K, int lda, int ldb, long ldc,
               long sB, long sC)
{
    __shared__ __align__(16) ushort As[128 * 32];
    __shared__ __align__(16) ushort Bs[128 * 32];
    const ushort* Bp = B + (long)blockIdx.z * sB;
    int tid = threadIdx.x;
    int l = tid & 63, w = tid >> 6;
    int l15 = l & 15, quad = l >> 4;
    int m0 = blockIdx.y * 128, n0 = blockIdx.x * 128;
    int wm = (w >> 1) * 64, wn = (w & 1) * 64;
    f32x4 acc[4][4] = {};

    int ob = tid * 16;                     // byte offset within a 4 KB issue
    int row = ob >> 6, colb = ob & 63;     // 64 B per 32-element k-row
    const char* ga0 = (const char*)(A  + (long)(m0 + row) * lda)      + colb;
    const char* ga1 = (const char*)(A  + (long)(m0 + row + 64) * lda) + colb;
    const char* gb0 = (const char*)(Bp + (long)(n0 + row) * ldb)      + colb;
    const char* gb1 = (const char*)(Bp + (long)(n0 + row + 64) * ldb) + colb;
    ushort* la0 = As + tid * 8;
    ushort* la1 = As + 2048 + tid * 8;
    ushort* lb0 = Bs + tid * 8;
    ushort* lb1 = Bs + 2048 + tid * 8;

    for (int k0 = 0; k0 < K; k0 += 32) {
        GLL16(ga0, la0); GLL16(ga1, la1);
        GLL16(gb0, lb0); GLL16(gb1, lb1);
        ga0 += 64; ga1 += 64; gb0 += 64; gb1 += 64;
        __syncthreads();
        short8 af[4], bf[4];
        #pragma unroll
        for (int i = 0; i < 4; ++i)
            af[i] = *(const short8*)(As + (wm + i * 16 + l15) * 32 + quad * 8);
        #pragma unroll
        for (int j = 0; j < 4; ++j)
            bf[j] = *(const short8*)(Bs + (wn + j * 16 + l15) * 32 + quad * 8);
        #pragma unroll
        for (int i = 0; i < 4; ++i)
            #pragma unroll
            for (int j = 0; j < 4; ++j)
                acc[i][j] = __builtin_amdgcn_mfma_f32_16x16x32_bf16(
                    af[i], bf[j], acc[i][j], 0, 0, 0);
        __syncthreads();
    }

    #pragma unroll
    for (int i = 0; i < 4; ++i) {
        #pragma unroll
        for (int j = 0; j < 4; ++j) {
            #pragma unroll
            for (int r = 0; r < 4; ++r) {
                long gm = m0 + wm + i * 16 + quad * 4 + r;
                long gn = n0 + wn + j * 16 + l15;
                float v = acc[i][j][r];
                if (OUT_MODE == 0) {
                    float* C = (float*)Cv + (long)blockIdx.z * sC;
                    C[gm * ldc + gn] = v;
                } else if (OUT_MODE == 1) {
                    ushort* C = (ushort*)Cv + (long)blockIdx.z * sC;
                    C[gm * ldc + gn] = f2bf(v);
                } else {
                    ushort* C = (ushort*)Cv + (long)blockIdx.z * sC;
                    C[gn * ldc + gm] = f2bf(v);   // transposed
                }
            }
        }
    }
}

// ---------------------------------------------------------------------------
// Row LayerNorm, fp32 in -> bf16 out.
// ---------------------------------------------------------------------------
__global__ __launch_bounds__(256)
void ln_rows_bf(const float* __restrict__ in, ushort* __restrict__ out,
                const float* __restrict__ g, const float* __restrict__ b,
                int n, int ld_in, int ld_out)
{
    long rowi = blockIdx.x;
    const float* x = in + rowi * ld_in;
    ushort* y = out + rowi * ld_out;
    int tid = threadIdx.x;
    float s = 0.f, ss = 0.f;
    for (int i = tid; i < n; i += 256) { float v = x[i]; s += v; ss += v * v; }
    #pragma unroll
    for (int off = 32; off > 0; off >>= 1) {
        s  += __shfl_xor(s, off);
        ss += __shfl_xor(ss, off);
    }
    __shared__ float sred[4], ssred[4];
    int wid = tid >> 6, lane = tid & 63;
    if (lane == 0) { sred[wid] = s; ssred[wid] = ss; }
    __syncthreads();
    s  = sred[0] + sred[1] + sred[2] + sred[3];
    ss = ssred[0] + ssred[1] + ssred[2] + ssred[3];
    float mu  = s / n;
    float var = ss / n - mu * mu;
    float r = 1.0f / sqrtf(var + LN_EPS);
    for (int i = tid; i < n; i += 256)
        y[i] = f2bf((x[i] - mu) * r * g[i] + b[i]);
}

// ---------------------------------------------------------------------------
// RoPE q: q_ropef [NROWS][NH*64] fp32 -> q_full[row][h][128..191] bf16
// ---------------------------------------------------------------------------
__global__ __launch_bounds__(256)
void rope_q(const float* __restrict__ qr, ushort* __restrict__ qfull,
            const int* __restrict__ pos)
{
    long idx = (long)blockIdx.x * 256 + threadIdx.x;
    if (idx >= (long)NROWS * NH * 32) return;
    int i = (int)(idx & 31);
    long rh = idx >> 5;          // row*16 + h
    int h = (int)(rh & 15);
    long rowi = rh >> 4;
    int s = (int)(rowi & (SS - 1));
    double ang = (double)pos[s] * exp(-(double)i * 0.28782313662425572);
    float c = (float)cos(ang), sn = (float)sin(ang);
    const float* p = qr + rowi * (NH * DR) + h * DR;
    float x1 = p[i], x2 = p[i + 32];
    ushort* o = qfull + (rowi * NH + h) * 192 + 128;
    o[i]      = f2bf(x1 * c - x2 * sn);
    o[i + 32] = f2bf(x1 * sn + x2 * c);
}

// ---------------------------------------------------------------------------
// RoPE k: kv_mix [NROWS][640] cols 512.. -> k_full[row][h][128..191] all h
// ---------------------------------------------------------------------------
__global__ __launch_bounds__(256)
void rope_k(const float* __restrict__ kvm, ushort* __restrict__ kfull,
            const int* __restrict__ pos)
{
    int idx = blockIdx.x * 256 + threadIdx.x;
    if (idx >= NROWS * 32) return;
    int i = idx & 31;
    long rowi = idx >> 5;
    int s = (int)(rowi & (SS - 1));
    double ang = (double)pos[s] * exp(-(double)i * 0.28782313662425572);
    float c = (float)cos(ang), sn = (float)sin(ang);
    const float* p = kvm + rowi * 640 + 512;
    float x1 = p[i], x2 = p[i + 32];
    ushort v1 = f2bf(x1 * c - x2 * sn);
    ushort v2 = f2bf(x1 * sn + x2 * c);
    ushort* o = kfull + rowi * NH * 192 + 128;
    #pragma unroll
    for (int h = 0; h < NH; ++h) {
        o[h * 192 + i]      = v1;
        o[h * 192 + i + 32] = v2;
    }
}

// ---------------------------------------------------------------------------
// MFMA flash attention. Per block: one (b,h), 64 q-rows. 256 threads, 4 waves.
// Q frags in registers; K (64x192) and V^T (128x64) staged in padded LDS.
// Online softmax in C-layout registers; P via LDS (same-wave) for PV.
// ---------------------------------------------------------------------------
#define FSCALE 0.07216878364870322f   // 1/sqrt(192)

__global__ __launch_bounds__(256)
void flash_mfma(const ushort* __restrict__ qf, const ushort* __restrict__ kf,
                const ushort* __restrict__ vt, ushort* __restrict__ attnv)
{
    __shared__ __align__(16) ushort Ks[64 * 200];   // row stride 400 B
    __shared__ __align__(16) ushort Vs[128 * 72];   // row stride 144 B
    __shared__ __align__(16) ushort Ps[64 * 72];
    int tid = threadIdx.x;
    int w = tid >> 6, l = tid & 63, l15 = l & 15, quad = l >> 4;
    int q0 = blockIdx.x * 64;
    int b = blockIdx.y >> 4, h = blockIdx.y & 15;

    // preload Q fragments (A-operand: m = l15, k = kk*32 + quad*8 + j)
    const ushort* qp = qf + ((long)(b * SS + q0 + 16 * w + l15) * NH + h) * 192 + quad * 8;
    short8 aq[6];
    #pragma unroll
    for (int kk = 0; kk < 6; ++kk) aq[kk] = *(const short8*)(qp + kk * 32);

    f32x4 o[8] = {};
    float mrow[4], lrow[4];
    #pragma unroll
    for (int r = 0; r < 4; ++r) { mrow[r] = -INFINITY; lrow[r] = 0.f; }

    const ushort* kbase0 = kf + ((long)(b * SS) * NH + h) * 192;
    const ushort* vbase0 = vt + (long)h * 128 * 4096 + (long)b * SS;

    for (int k0 = 0; k0 < SS; k0 += 64) {
        const ushort* kb = kbase0 + (long)k0 * NH * 192;
        #pragma unroll
        for (int it = 0; it < 6; ++it) {
            int c = tid + it * 256;          // 1536 chunks of 8 bf16
            int r = c / 24, c8 = c % 24;
            short8 x = *(const short8*)(kb + (long)r * NH * 192 + c8 * 8);
            *(short8*)&Ks[r * 200 + c8 * 8] = x;
        }
        const ushort* vb = vbase0 + k0;
        #pragma unroll
        for (int it = 0; it < 4; ++it) {
            int c = tid + it * 256;          // 1024 chunks
            int vv = c >> 3, k8 = c & 7;
            short8 x = *(const short8*)(vb + (long)vv * 4096 + k8 * 8);
            *(short8*)&Vs[vv * 72 + k8 * 8] = x;
        }
        __syncthreads();

        // QK^T: C[q=quad*4+r][kcol=j*16+l15]
        f32x4 sc[4] = {};
        #pragma unroll
        for (int kk = 0; kk < 6; ++kk) {
            #pragma unroll
            for (int j = 0; j < 4; ++j) {
                short8 bfr = *(const short8*)&Ks[(j * 16 + l15) * 200 + kk * 32 + quad * 8];
                sc[j] = __builtin_amdgcn_mfma_f32_16x16x32_bf16(aq[kk], bfr, sc[j], 0, 0, 0);
            }
        }

        // online softmax per q-row + P write (bf16)
        #pragma unroll
        for (int r = 0; r < 4; ++r) {
            float s0 = sc[0][r] * FSCALE, s1 = sc[1][r] * FSCALE;
            float s2 = sc[2][r] * FSCALE, s3 = sc[3][r] * FSCALE;
            float mx = fmaxf(fmaxf(s0, s1), fmaxf(s2, s3));
            mx = fmaxf(mx, __shfl_xor(mx, 1));
            mx = fmaxf(mx, __shfl_xor(mx, 2));
            mx = fmaxf(mx, __shfl_xor(mx, 4));
            mx = fmaxf(mx, __shfl_xor(mx, 8));
            float mnew = fmaxf(mrow[r], mx);
            float alpha = __expf(mrow[r] - mnew);
            mrow[r] = mnew;
            float p0 = __expf(s0 - mnew), p1 = __expf(s1 - mnew);
            float p2 = __expf(s2 - mnew), p3 = __expf(s3 - mnew);
            float ps = p0 + p1 + p2 + p3;
            ps += __shfl_xor(ps, 1);
            ps += __shfl_xor(ps, 2);
            ps += __shfl_xor(ps, 4);
            ps += __shfl_xor(ps, 8);
            lrow[r] = lrow[r] * alpha + ps;
            #pragma unroll
            for (int v8 = 0; v8 < 8; ++v8) o[v8][r] *= alpha;
            int prow = (16 * w + quad * 4 + r) * 72;
            Ps[prow + l15]      = f2bf(p0);
            Ps[prow + 16 + l15] = f2bf(p1);
            Ps[prow + 32 + l15] = f2bf(p2);
            Ps[prow + 48 + l15] = f2bf(p3);
        }

        // PV: O[q][v] += P[q][k] * V[k][v]; P rows are same-wave (no barrier)
        #pragma unroll
        for (int ks = 0; ks < 2; ++ks) {
            short8 pa = *(const short8*)&Ps[(16 * w + l15) * 72 + ks * 32 + quad * 8];
            #pragma unroll
            for (int v8 = 0; v8 < 8; ++v8) {
                short8 bv = *(const short8*)&Vs[(v8 * 16 + l15) * 72 + ks * 32 + quad * 8];
                o[v8] = __builtin_amdgcn_mfma_f32_16x16x32_bf16(pa, bv, o[v8], 0, 0, 0);
            }
        }
        __syncthreads();
    }

    #pragma unroll
    for (int r = 0; r < 4; ++r) {
        float inv = 1.0f / lrow[r];
        long rowi = (long)(b * SS + q0 + 16 * w + quad * 4 + r);
        ushort* op = attnv + (rowi * NH + h) * 128;
        #pragma unroll
        for (int v8 = 0; v8 < 8; ++v8)
            op[v8 * 16 + l15] = f2bf(o[v8][r] * inv);
    }
}

// ---------------------------------------------------------------------------

extern "C" void kernel_launch(void* const* d_in, const int* in_sizes, int n_in,
                              void* d_out, int out_size, void* d_ws, size_t ws_size,
                              hipStream_t stream) {
    const float* hs       = (const float*)d_in[0];
    const float* w_qa     = (const float*)d_in[1];
    const float* ln_qa_g  = (const float*)d_in[2];
    const float* ln_qa_b  = (const float*)d_in[3];
    const float* w_qb     = (const float*)d_in[4];
    const float* w_qrope  = (const float*)d_in[5];
    const float* w_kva    = (const float*)d_in[6];
    const float* ln_kva_g = (const float*)d_in[7];
    const float* ln_kva_b = (const float*)d_in[8];
    const float* w_kvb    = (const float*)d_in[9];
    const float* w_o      = (const float*)d_in[10];
    const int*   pos      = (const int*)d_in[11];
    float* out = (float*)d_out;

    char* W = (char*)d_ws;
    // byte offsets (w_o_bf aliases hs_bf region; q_ropef aliases q_lat_f)
    ushort* hs_bf     = (ushort*)(W + 0);            // 16,777,216 B
    ushort* w_o_bf    = (ushort*)(W + 0);            //  8,388,608 B (after G4)
    ushort* w_qa_bf   = (ushort*)(W + 16777216);     //  6,291,456
    ushort* w_qb_bf   = (ushort*)(W + 23068672);     //  6,291,456
    ushort* w_qrope_bf= (ushort*)(W + 29360128);     //  3,145,728
    ushort* w_kva_bf  = (ushort*)(W + 32505856);     //  2,621,440
    ushort* w_kvb_bf  = (ushort*)(W + 35127296);     //  4,194,304
    float*  q_lat_f   = (float*)(W + 39321600);      // 25,165,824
    float*  q_ropef   = (float*)(W + 39321600);      // alias, 16,777,216
    ushort* q_lat_bf  = (ushort*)(W + 64487424);     // 12,582,912
    float*  kv_mix    = (float*)(W + 77070336);      // 10,485,760
    ushort* kv_lat_bf = (ushort*)(W + 87556096);     //  4,194,304
    ushort* q_full    = (ushort*)(W + 91750400);     // 25,165,824
    ushort* k_full    = (ushort*)(W + 116916224);    // 25,165,824
    ushort* v_exp_t   = (ushort*)(W + 142082048);    // 16,777,216
    ushort* attnv_bf  = (ushort*)(W + 158859264);    // 16,777,216  (end 175,636,480)

    dim3 blk(256);

    // converts
    cvt_bf16<<<dim3(8192), blk, 0, stream>>>(hs,      hs_bf,      2097152);
    cvt_bf16<<<dim3(3072), blk, 0, stream>>>(w_qa,    w_qa_bf,     786432);
    cvt_bf16<<<dim3(3072), blk, 0, stream>>>(w_qb,    w_qb_bf,     786432);
    cvt_bf16<<<dim3(1536), blk, 0, stream>>>(w_qrope, w_qrope_bf,  393216);
    cvt_bf16<<<dim3(2048), blk, 0, stream>>>(w_kvb,   w_kvb_bf,    524288);
    cvt_pad_kva<<<dim3(1280), blk, 0, stream>>>(w_kva, w_kva_bf);

    // G1: q_mixed = hs @ w_qa^T -> fp32 [4096][1536]
    gemm_bf16<0><<<dim3(12, 32, 1), blk, 0, stream>>>(
        hs_bf, w_qa_bf, q_lat_f, D_MODEL, D_MODEL, D_MODEL, Q_LORA, 0, 0);
    // LN qa -> bf16
    ln_rows_bf<<<dim3(NROWS), blk, 0, stream>>>(
        q_lat_f, q_lat_bf, ln_qa_g, ln_qa_b, Q_LORA, Q_LORA, Q_LORA);
    // G2 (batched over heads): q_nope -> q_full[:, h, 0:128] bf16
    gemm_bf16<1><<<dim3(1, 32, 16), blk, 0, stream>>>(
        q_lat_bf, w_qb_bf, q_full, Q_LORA, Q_LORA, Q_LORA, NH * 192,
        (long)128 * Q_LORA, 192);
    // G3: q_ropef fp32 [4096][1024]
    gemm_bf16<0><<<dim3(8, 32, 1), blk, 0, stream>>>(
        q_lat_bf, w_qrope_bf, q_ropef, Q_LORA, Q_LORA, Q_LORA, NH * DR, 0, 0);
    // G4: kv_mix fp32 [4096][640] (padded N)
    gemm_bf16<0><<<dim3(5, 32, 1), blk, 0, stream>>>(
        hs_bf, w_kva_bf, kv_mix, D_MODEL, D_MODEL, D_MODEL, 640, 0, 0);
    // w_o convert (hs_bf region now dead)
    cvt_bf16<<<dim3(4096), blk, 0, stream>>>(w_o, w_o_bf, 1048576);
    // LN kva -> bf16
    ln_rows_bf<<<dim3(NROWS), blk, 0, stream>>>(
        kv_mix, kv_lat_bf, ln_kva_g, ln_kva_b, KV_LORA, 640, KV_LORA);
    // RoPE
    rope_q<<<dim3(8192), blk, 0, stream>>>(q_ropef, q_full, pos);
    rope_k<<<dim3(512), blk, 0, stream>>>(kv_mix, k_full, pos);
    // G5 (batched): k_exp -> k_full[:, h, 0:128] bf16
    gemm_bf16<1><<<dim3(1, 32, 16), blk, 0, stream>>>(
        kv_lat_bf, w_kvb_bf, k_full, KV_LORA, KV_LORA, KV_LORA, NH * 192,
        (long)128 * KV_LORA, 192);
    // G6 (batched): v_exp -> v_exp_t [h][v][row] bf16 (transposed store)
    gemm_bf16<2><<<dim3(1, 32, 16), blk, 0, stream>>>(
        kv_lat_bf, w_kvb_bf + (long)NH * DN * KV_LORA, v_exp_t,
        KV_LORA, KV_LORA, KV_LORA, NROWS, (long)128 * KV_LORA, (long)128 * NROWS);
    // flash attention -> attnv bf16 [4096][2048]
    flash_mfma<<<dim3(SS / 64, BB * NH), blk, 0, stream>>>(
        q_full, k_full, v_exp_t, attnv_bf);
    // G7: out = attnv @ w_o^T -> fp32
    gemm_bf16<0><<<dim3(16, 32, 1), blk, 0, stream>>>(
        attnv_bf, w_o_bf, out, NH * DV, NH * DV, NH * DV, D_MODEL, 0, 0);
}

// Round 4
// 567.880 us; speedup vs baseline: 10.7028x; 1.4271x over previous
//
#include <hip/hip_runtime.h>
#include <math.h>

#define D_MODEL 2048
#define NH 16
#define Q_LORA 1536
#define KV_LORA 512
#define DN 128
#define DR 64
#define DV 128
#define BB 2
#define SS 2048
#define NROWS (BB*SS)
#define LN_EPS 1e-5f

typedef __attribute__((ext_vector_type(8))) short short8;
typedef __attribute__((ext_vector_type(4))) float f32x4;

__device__ __forceinline__ ushort f2bf(float f) {
    unsigned int u = __float_as_uint(f);
    u = u + 0x7fffu + ((u >> 16) & 1u);   // round-to-nearest-even
    return (ushort)(u >> 16);
}

// ---------------------------------------------------------------------------
// Fused fp32 -> bf16 converter for 5 arrays + padded w_kva.
// ---------------------------------------------------------------------------
__device__ __forceinline__ void cv4(const float* __restrict__ s,
                                    ushort* __restrict__ d, long i) {
    float4 v = ((const float4*)s)[i];
    ushort4 o;
    o.x = f2bf(v.x); o.y = f2bf(v.y); o.z = f2bf(v.z); o.w = f2bf(v.w);
    ((ushort4*)d)[i] = o;
}

__global__ __launch_bounds__(256)
void cvt_all(const float* __restrict__ hs,     const float* __restrict__ w_qa,
             const float* __restrict__ w_qb,   const float* __restrict__ w_qrope,
             const float* __restrict__ w_kvb,  const float* __restrict__ w_kva,
             ushort* __restrict__ hs_bf,       ushort* __restrict__ w_qa_bf,
             ushort* __restrict__ w_qb_bf,     ushort* __restrict__ w_qrope_bf,
             ushort* __restrict__ w_kvb_bf,    ushort* __restrict__ w_kva_bf)
{
    long i = (long)blockIdx.x * 256 + threadIdx.x;
    if (i < 2097152) { cv4(hs, hs_bf, i); return; }
    i -= 2097152;
    if (i < 786432) { cv4(w_qa, w_qa_bf, i); return; }
    i -= 786432;
    if (i < 786432) { cv4(w_qb, w_qb_bf, i); return; }
    i -= 786432;
    if (i < 393216) { cv4(w_qrope, w_qrope_bf, i); return; }
    i -= 393216;
    if (i < 524288) { cv4(w_kvb, w_kvb_bf, i); return; }
    i -= 524288;
    if (i >= 327680) return;
    // w_kva: 576x2048 -> padded 640x2048 (zero fill)
    long e = i * 4;
    int row = (int)(e >> 11), col = (int)(e & 2047);
    ushort4 o;
    if (row < 576) {
        float4 v = *(const float4*)(w_kva + (long)row * 2048 + col);
        o.x = f2bf(v.x); o.y = f2bf(v.y); o.z = f2bf(v.z); o.w = f2bf(v.w);
    } else { o.x = 0; o.y = 0; o.z = 0; o.w = 0; }
    *(ushort4*)(w_kva_bf + (long)row * 2048 + col) = o;
}

__global__ __launch_bounds__(256)
void cvt_bf16(const float* __restrict__ in, ushort* __restrict__ out, long n4)
{
    long i = (long)blockIdx.x * 256 + threadIdx.x;
    if (i >= n4) return;
    cv4(in, out, i);
}

// ---------------------------------------------------------------------------
// Shared bf16 MFMA GEMM core: C128x128 = A @ B^T tile, BK=32, 256 thr, GLL16.
// ---------------------------------------------------------------------------
#define GLL16(g, l) \
    __builtin_amdgcn_global_load_lds((const __attribute__((address_space(1))) void*)(g), \
                                     (__attribute__((address_space(3))) void*)(l), 16, 0, 0)

__device__ __forceinline__ void gemm_core(const ushort* __restrict__ A,
    const ushort* __restrict__ Bp, ushort* As, ushort* Bs,
    int K, int lda, int ldb, int m0, int n0, int tid, f32x4 acc[4][4])
{
    int l = tid & 63, w = tid >> 6;
    int l15 = l & 15, quad = l >> 4;
    int wm = (w >> 1) * 64, wn = (w & 1) * 64;
    int ob = tid * 16;
    int row = ob >> 6, colb = ob & 63;
    const char* ga0 = (const char*)(A  + (long)(m0 + row) * lda)      + colb;
    const char* ga1 = (const char*)(A  + (long)(m0 + row + 64) * lda) + colb;
    const char* gb0 = (const char*)(Bp + (long)(n0 + row) * ldb)      + colb;
    const char* gb1 = (const char*)(Bp + (long)(n0 + row + 64) * ldb) + colb;
    ushort* la0 = As + tid * 8;
    ushort* la1 = As + 2048 + tid * 8;
    ushort* lb0 = Bs + tid * 8;
    ushort* lb1 = Bs + 2048 + tid * 8;

    for (int k0 = 0; k0 < K; k0 += 32) {
        GLL16(ga0, la0); GLL16(ga1, la1);
        GLL16(gb0, lb0); GLL16(gb1, lb1);
        ga0 += 64; ga1 += 64; gb0 += 64; gb1 += 64;
        __syncthreads();
        short8 af[4], bf[4];
        #pragma unroll
        for (int i = 0; i < 4; ++i)
            af[i] = *(const short8*)(As + (wm + i * 16 + l15) * 32 + quad * 8);
        #pragma unroll
        for (int j = 0; j < 4; ++j)
            bf[j] = *(const short8*)(Bs + (wn + j * 16 + l15) * 32 + quad * 8);
        #pragma unroll
        for (int i = 0; i < 4; ++i)
            #pragma unroll
            for (int j = 0; j < 4; ++j)
                acc[i][j] = __builtin_amdgcn_mfma_f32_16x16x32_bf16(
                    af[i], bf[j], acc[i][j], 0, 0, 0);
        __syncthreads();
    }
}

// plain fp32-out GEMM (G1, G4, G7)
__global__ __launch_bounds__(256)
void gemm_f32out(const ushort* __restrict__ A, const ushort* __restrict__ B,
                 float* __restrict__ C, int K, int lda, int ldb, int ldc)
{
    __shared__ __align__(16) ushort As[128 * 32];
    __shared__ __align__(16) ushort Bs[128 * 32];
    int tid = threadIdx.x;
    int m0 = blockIdx.y * 128, n0 = blockIdx.x * 128;
    f32x4 acc[4][4] = {};
    gemm_core(A, B, As, Bs, K, lda, ldb, m0, n0, tid, acc);
    int l = tid & 63, w = tid >> 6;
    int l15 = l & 15, quad = l >> 4;
    int wm = (w >> 1) * 64, wn = (w & 1) * 64;
    #pragma unroll
    for (int i = 0; i < 4; ++i)
        #pragma unroll
        for (int j = 0; j < 4; ++j)
            #pragma unroll
            for (int r = 0; r < 4; ++r) {
                long gm = m0 + wm + i * 16 + quad * 4 + r;
                long gn = n0 + wn + j * 16 + l15;
                C[gm * ldc + gn] = acc[i][j][r];
            }
}

// fused q_nope + q_rope GEMM: N region [0,2048)=w_qb -> q_full bf16,
// [2048,3072)=w_qrope -> q_ropef fp32
__global__ __launch_bounds__(256)
void gemm_q23(const ushort* __restrict__ A, const ushort* __restrict__ Bqb,
              const ushort* __restrict__ Bqr, ushort* __restrict__ qfull,
              float* __restrict__ qropef)
{
    __shared__ __align__(16) ushort As[128 * 32];
    __shared__ __align__(16) ushort Bs[128 * 32];
    int tid = threadIdx.x;
    int m0 = blockIdx.y * 128, n0 = blockIdx.x * 128;
    const ushort* Bp = (n0 < 2048) ? Bqb + (long)n0 * Q_LORA
                                   : Bqr + (long)(n0 - 2048) * Q_LORA;
    f32x4 acc[4][4] = {};
    gemm_core(A, Bp, As, Bs, Q_LORA, Q_LORA, Q_LORA, m0, 0, tid, acc);
    int l = tid & 63, w = tid >> 6;
    int l15 = l & 15, quad = l >> 4;
    int wm = (w >> 1) * 64, wn = (w & 1) * 64;
    if (n0 < 2048) {
        int head = n0 >> 7;
        #pragma unroll
        for (int i = 0; i < 4; ++i)
            #pragma unroll
            for (int j = 0; j < 4; ++j)
                #pragma unroll
                for (int r = 0; r < 4; ++r) {
                    long gm = m0 + wm + i * 16 + quad * 4 + r;
                    int c = wn + j * 16 + l15;
                    qfull[(gm * NH + head) * 192 + c] = f2bf(acc[i][j][r]);
                }
    } else {
        int nb = n0 - 2048;
        #pragma unroll
        for (int i = 0; i < 4; ++i)
            #pragma unroll
            for (int j = 0; j < 4; ++j)
                #pragma unroll
                for (int r = 0; r < 4; ++r) {
                    long gm = m0 + wm + i * 16 + quad * 4 + r;
                    qropef[gm * 1024 + nb + wn + j * 16 + l15] = acc[i][j][r];
                }
    }
}

// fused k_up/v_up GEMM over w_kvb: [0,2048) -> k_full bf16 scalar,
// [2048,4096) -> v_exp_t packed transposed bf16
__global__ __launch_bounds__(256)
void gemm_kv56(const ushort* __restrict__ A, const ushort* __restrict__ B,
               ushort* __restrict__ kfull, ushort* __restrict__ vt)
{
    __shared__ __align__(16) ushort As[128 * 32];
    __shared__ __align__(16) ushort Bs[128 * 32];
    int tid = threadIdx.x;
    int m0 = blockIdx.y * 128, n0 = blockIdx.x * 128;
    const ushort* Bp = B + (long)n0 * KV_LORA;
    f32x4 acc[4][4] = {};
    gemm_core(A, Bp, As, Bs, KV_LORA, KV_LORA, KV_LORA, m0, 0, tid, acc);
    int l = tid & 63, w = tid >> 6;
    int l15 = l & 15, quad = l >> 4;
    int wm = (w >> 1) * 64, wn = (w & 1) * 64;
    if (n0 < 2048) {
        int head = n0 >> 7;
        #pragma unroll
        for (int i = 0; i < 4; ++i)
            #pragma unroll
            for (int j = 0; j < 4; ++j)
                #pragma unroll
                for (int r = 0; r < 4; ++r) {
                    long gm = m0 + wm + i * 16 + quad * 4 + r;
                    int c = wn + j * 16 + l15;
                    kfull[(gm * NH + head) * 192 + c] = f2bf(acc[i][j][r]);
                }
    } else {
        int head = (n0 >> 7) - 16;
        #pragma unroll
        for (int i = 0; i < 4; ++i)
            #pragma unroll
            for (int j = 0; j < 4; ++j) {
                long gm0 = m0 + wm + i * 16 + quad * 4;
                int c = wn + j * 16 + l15;        // v channel
                ushort4 p;
                p.x = f2bf(acc[i][j][0]); p.y = f2bf(acc[i][j][1]);
                p.z = f2bf(acc[i][j][2]); p.w = f2bf(acc[i][j][3]);
                *(ushort4*)(vt + (long)head * 128 * 4096 + (long)c * 4096 + gm0) = p;
            }
    }
}

// ---------------------------------------------------------------------------
// Row LayerNorm, fp32 in -> bf16 out.
// ---------------------------------------------------------------------------
__global__ __launch_bounds__(256)
void ln_rows_bf(const float* __restrict__ in, ushort* __restrict__ out,
                const float* __restrict__ g, const float* __restrict__ b,
                int n, int ld_in, int ld_out)
{
    long rowi = blockIdx.x;
    const float* x = in + rowi * ld_in;
    ushort* y = out + rowi * ld_out;
    int tid = threadIdx.x;
    float s = 0.f, ss = 0.f;
    for (int i = tid; i < n; i += 256) { float v = x[i]; s += v; ss += v * v; }
    #pragma unroll
    for (int off = 32; off > 0; off >>= 1) {
        s  += __shfl_xor(s, off);
        ss += __shfl_xor(ss, off);
    }
    __shared__ float sred[4], ssred[4];
    int wid = tid >> 6, lane = tid & 63;
    if (lane == 0) { sred[wid] = s; ssred[wid] = ss; }
    __syncthreads();
    s  = sred[0] + sred[1] + sred[2] + sred[3];
    ss = ssred[0] + ssred[1] + ssred[2] + ssred[3];
    float mu  = s / n;
    float var = ss / n - mu * mu;
    float r = 1.0f / sqrtf(var + LN_EPS);
    for (int i = tid; i < n; i += 256)
        y[i] = f2bf((x[i] - mu) * r * g[i] + b[i]);
}

// ---------------------------------------------------------------------------
// Fused RoPE (q + k broadcast).
// ---------------------------------------------------------------------------
__global__ __launch_bounds__(256)
void rope_all(const float* __restrict__ qr, const float* __restrict__ kvm,
              ushort* __restrict__ qfull, ushort* __restrict__ kfull,
              const int* __restrict__ pos)
{
    long idx = (long)blockIdx.x * 256 + threadIdx.x;
    if (idx < (long)NROWS * NH * 32) {
        int i = (int)(idx & 31);
        long rh = idx >> 5;
        int h = (int)(rh & 15);
        long rowi = rh >> 4;
        int s = (int)(rowi & (SS - 1));
        double ang = (double)pos[s] * exp(-(double)i * 0.28782313662425572);
        float c = (float)cos(ang), sn = (float)sin(ang);
        const float* p = qr + rowi * (NH * DR) + h * DR;
        float x1 = p[i], x2 = p[i + 32];
        ushort* o = qfull + (rowi * NH + h) * 192 + 128;
        o[i]      = f2bf(x1 * c - x2 * sn);
        o[i + 32] = f2bf(x1 * sn + x2 * c);
        return;
    }
    idx -= (long)NROWS * NH * 32;
    if (idx >= (long)NROWS * 32) return;
    int i = (int)(idx & 31);
    long rowi = idx >> 5;
    int s = (int)(rowi & (SS - 1));
    double ang = (double)pos[s] * exp(-(double)i * 0.28782313662425572);
    float c = (float)cos(ang), sn = (float)sin(ang);
    const float* p = kvm + rowi * 640 + 512;
    float x1 = p[i], x2 = p[i + 32];
    ushort v1 = f2bf(x1 * c - x2 * sn);
    ushort v2 = f2bf(x1 * sn + x2 * c);
    ushort* o = kfull + rowi * NH * 192 + 128;
    #pragma unroll
    for (int h = 0; h < NH; ++h) {
        o[h * 192 + i]      = v1;
        o[h * 192 + i + 32] = v2;
    }
}

// ---------------------------------------------------------------------------
// MFMA flash attention v2: 512 thr (8 waves), TQ=128, TK=64.
// XOR-swizzled unpadded K/V LDS; register prefetch; ones-column row-sum.
// Grid (32 bh, 16 qb) so all q-blocks of a head share an XCD (linear%8=bh%8).
// ---------------------------------------------------------------------------
#define FSCALE 0.07216878364870322f   // 1/sqrt(192)

__global__ __launch_bounds__(512, 4)
void flash_mfma(const ushort* __restrict__ qf, const ushort* __restrict__ kf,
                const ushort* __restrict__ vt, ushort* __restrict__ attnv)
{
    __shared__ __align__(16) ushort Ks[64 * 192];    // 24.0 KB, swizzled
    __shared__ __align__(16) ushort Vs[144 * 64];    // 18.0 KB, swizzled (+ones rows)
    __shared__ __align__(16) ushort Ps[128 * 72];    // 18.0 KB, padded
    int tid = threadIdx.x;
    int w = tid >> 6, l = tid & 63, l15 = l & 15, quad = l >> 4;
    int bh = blockIdx.x;
    int b = bh >> 4, h = bh & 15;
    int q0 = blockIdx.y * 128;

    // init ones/zero rows v=128..143 (row 128 = 1.0, rest 0); swizzle-invariant
    {
        int e = 8192 + tid * 2;
        ushort2 iv;
        iv.x = (e     < 8256) ? (ushort)0x3F80 : (ushort)0;
        iv.y = (e + 1 < 8256) ? (ushort)0x3F80 : (ushort)0;
        *(ushort2*)&Vs[e] = iv;
    }

    // Q fragments: wave w owns q rows q0+16w .. q0+16w+15
    const ushort* qp = qf + ((long)(b * SS + q0 + 16 * w + l15) * NH + h) * 192 + quad * 8;
    short8 aq[6];
    #pragma unroll
    for (int kk = 0; kk < 6; ++kk) aq[kk] = *(const short8*)(qp + kk * 32);

    f32x4 o[8] = {};
    f32x4 osum = {};
    float mrow[4];
    #pragma unroll
    for (int r = 0; r < 4; ++r) mrow[r] = -INFINITY;

    const ushort* kbase = kf + ((long)(b * SS) * NH + h) * 192;
    const ushort* vbase = vt + (long)h * 128 * 4096 + (long)b * SS;

    // staging thread mapping
    int r0k = tid >> 3, subk = tid & 7;   // K: 64 rows x 24 chunks, 3/thread
    int v0  = tid >> 2, subv = tid & 3;   // V: 128 rows x 8 chunks, 2/thread
    const ushort* kgp = kbase + (long)r0k * (NH * 192);
    const ushort* vgp = vbase + (long)v0 * 4096;

    short8 pk[3], pv[2];
    #pragma unroll
    for (int it = 0; it < 3; ++it)
        pk[it] = *(const short8*)(kgp + (subk + 8 * it) * 8);
    #pragma unroll
    for (int it = 0; it < 2; ++it)
        pv[it] = *(const short8*)(vgp + (subv + 4 * it) * 8);

    int ksw = r0k & 7, vsw = v0 & 7;

    for (int k0 = 0; k0 < SS; k0 += 64) {
        __syncthreads();   // prior compute done reading Ks/Vs
        #pragma unroll
        for (int it = 0; it < 3; ++it)
            *(short8*)&Ks[r0k * 192 + ((subk + 8 * it) ^ ksw) * 8] = pk[it];
        #pragma unroll
        for (int it = 0; it < 2; ++it)
            *(short8*)&Vs[v0 * 64 + ((subv + 4 * it) ^ vsw) * 8] = pv[it];
        __syncthreads();
        if (k0 + 64 < SS) {   // prefetch next tile (loads in flight during compute)
            const ushort* kg = kgp + (long)(k0 + 64) * (NH * 192);
            const ushort* vg = vgp + (k0 + 64);
            #pragma unroll
            for (int it = 0; it < 3; ++it)
                pk[it] = *(const short8*)(kg + (subk + 8 * it) * 8);
            #pragma unroll
            for (int it = 0; it < 2; ++it)
                pv[it] = *(const short8*)(vg + (subv + 4 * it) * 8);
        }

        // QK^T: C[q=quad*4+r][kcol=j*16+l15]
        f32x4 sc[4] = {};
        #pragma unroll
        for (int kk = 0; kk < 6; ++kk) {
            #pragma unroll
            for (int j = 0; j < 4; ++j) {
                int krow = j * 16 + l15;
                short8 bfr = *(const short8*)&Ks[krow * 192 + (((kk * 4 + quad) ^ (krow & 7))) * 8];
                sc[j] = __builtin_amdgcn_mfma_f32_16x16x32_bf16(aq[kk], bfr, sc[j], 0, 0, 0);
            }
        }

        // online softmax (max via 4 shuffles; sum via ones-column MFMA below)
        #pragma unroll
        for (int r = 0; r < 4; ++r) {
            float s0 = sc[0][r] * FSCALE, s1 = sc[1][r] * FSCALE;
            float s2 = sc[2][r] * FSCALE, s3 = sc[3][r] * FSCALE;
            float mx = fmaxf(fmaxf(s0, s1), fmaxf(s2, s3));
            mx = fmaxf(mx, __shfl_xor(mx, 1));
            mx = fmaxf(mx, __shfl_xor(mx, 2));
            mx = fmaxf(mx, __shfl_xor(mx, 4));
            mx = fmaxf(mx, __shfl_xor(mx, 8));
            float mnew = fmaxf(mrow[r], mx);
            float alpha = __expf(mrow[r] - mnew);
            mrow[r] = mnew;
            float p0 = __expf(s0 - mnew), p1 = __expf(s1 - mnew);
            float p2 = __expf(s2 - mnew), p3 = __expf(s3 - mnew);
            #pragma unroll
            for (int v8 = 0; v8 < 8; ++v8) o[v8][r] *= alpha;
            osum[r] *= alpha;
            int prow = (16 * w + quad * 4 + r) * 72;
            Ps[prow + l15]      = f2bf(p0);
            Ps[prow + 16 + l15] = f2bf(p1);
            Ps[prow + 32 + l15] = f2bf(p2);
            Ps[prow + 48 + l15] = f2bf(p3);
        }

        // PV + row-sum (same-wave Ps, no barrier needed)
        #pragma unroll
        for (int ks = 0; ks < 2; ++ks) {
            short8 pa = *(const short8*)&Ps[(16 * w + l15) * 72 + ks * 32 + quad * 8];
            #pragma unroll
            for (int v8 = 0; v8 < 8; ++v8) {
                int vrow = v8 * 16 + l15;
                short8 bv = *(const short8*)&Vs[vrow * 64 + (((ks * 4 + quad) ^ (vrow & 7))) * 8];
                o[v8] = __builtin_amdgcn_mfma_f32_16x16x32_bf16(pa, bv, o[v8], 0, 0, 0);
            }
            {
                int vrow = 128 + l15;
                short8 bv = *(const short8*)&Vs[vrow * 64 + (((ks * 4 + quad) ^ (vrow & 7))) * 8];
                osum = __builtin_amdgcn_mfma_f32_16x16x32_bf16(pa, bv, osum, 0, 0, 0);
            }
        }
    }

    #pragma unroll
    for (int r = 0; r < 4; ++r) {
        float lsum = __shfl(osum[r], l & 48);   // broadcast from l15==0 of this quad
        float inv = 1.0f / lsum;
        long rowi = (long)(b * SS) + q0 + 16 * w + quad * 4 + r;
        ushort* op = attnv + (rowi * NH + h) * 128;
        #pragma unroll
        for (int v8 = 0; v8 < 8; ++v8)
            op[v8 * 16 + l15] = f2bf(o[v8][r] * inv);
    }
}

// ---------------------------------------------------------------------------

extern "C" void kernel_launch(void* const* d_in, const int* in_sizes, int n_in,
                              void* d_out, int out_size, void* d_ws, size_t ws_size,
                              hipStream_t stream) {
    const float* hs       = (const float*)d_in[0];
    const float* w_qa     = (const float*)d_in[1];
    const float* ln_qa_g  = (const float*)d_in[2];
    const float* ln_qa_b  = (const float*)d_in[3];
    const float* w_qb     = (const float*)d_in[4];
    const float* w_qrope  = (const float*)d_in[5];
    const float* w_kva    = (const float*)d_in[6];
    const float* ln_kva_g = (const float*)d_in[7];
    const float* ln_kva_b = (const float*)d_in[8];
    const float* w_kvb    = (const float*)d_in[9];
    const float* w_o      = (const float*)d_in[10];
    const int*   pos      = (const int*)d_in[11];
    float* out = (float*)d_out;

    char* W = (char*)d_ws;
    ushort* hs_bf     = (ushort*)(W + 0);            // 16,777,216 B
    ushort* w_o_bf    = (ushort*)(W + 0);            //  8,388,608 B (after G4)
    ushort* w_qa_bf   = (ushort*)(W + 16777216);     //  6,291,456
    ushort* w_qb_bf   = (ushort*)(W + 23068672);     //  6,291,456
    ushort* w_qrope_bf= (ushort*)(W + 29360128);     //  3,145,728
    ushort* w_kva_bf  = (ushort*)(W + 32505856);     //  2,621,440
    ushort* w_kvb_bf  = (ushort*)(W + 35127296);     //  4,194,304
    float*  q_lat_f   = (float*)(W + 39321600);      // 25,165,824
    float*  q_ropef   = (float*)(W + 39321600);      // alias, 16,777,216
    ushort* q_lat_bf  = (ushort*)(W + 64487424);     // 12,582,912
    float*  kv_mix    = (float*)(W + 77070336);      // 10,485,760
    ushort* kv_lat_bf = (ushort*)(W + 87556096);     //  4,194,304
    ushort* q_full    = (ushort*)(W + 91750400);     // 25,165,824
    ushort* k_full    = (ushort*)(W + 116916224);    // 25,165,824
    ushort* v_exp_t   = (ushort*)(W + 142082048);    // 16,777,216
    ushort* attnv_bf  = (ushort*)(W + 158859264);    // 16,777,216

    dim3 blk(256);

    // 1. all converts (except w_o)
    cvt_all<<<dim3(19200), blk, 0, stream>>>(
        hs, w_qa, w_qb, w_qrope, w_kvb, w_kva,
        hs_bf, w_qa_bf, w_qb_bf, w_qrope_bf, w_kvb_bf, w_kva_bf);
    // 2. G1: q_mixed = hs @ w_qa^T -> fp32
    gemm_f32out<<<dim3(12, 32), blk, 0, stream>>>(
        hs_bf, w_qa_bf, q_lat_f, D_MODEL, D_MODEL, D_MODEL, Q_LORA);
    // 3. LN qa -> bf16
    ln_rows_bf<<<dim3(NROWS), blk, 0, stream>>>(
        q_lat_f, q_lat_bf, ln_qa_g, ln_qa_b, Q_LORA, Q_LORA, Q_LORA);
    // 4. fused q_nope/q_rope GEMM
    gemm_q23<<<dim3(24, 32), blk, 0, stream>>>(
        q_lat_bf, w_qb_bf, w_qrope_bf, q_full, q_ropef);
    // 5. G4: kv_mix fp32 [4096][640]
    gemm_f32out<<<dim3(5, 32), blk, 0, stream>>>(
        hs_bf, w_kva_bf, kv_mix, D_MODEL, D_MODEL, D_MODEL, 640);
    // 6. w_o convert (hs_bf region now dead); w_o = 2048*2048 = 1,048,576 float4
    cvt_bf16<<<dim3(4096), blk, 0, stream>>>(w_o, w_o_bf, 1048576);
    // 7. LN kva -> bf16
    ln_rows_bf<<<dim3(NROWS), blk, 0, stream>>>(
        kv_mix, kv_lat_bf, ln_kva_g, ln_kva_b, KV_LORA, 640, KV_LORA);
    // 8. fused RoPE
    rope_all<<<dim3(8704), blk, 0, stream>>>(q_ropef, kv_mix, q_full, k_full, pos);
    // 9. fused k_up/v_up GEMM
    gemm_kv56<<<dim3(32, 32), blk, 0, stream>>>(
        kv_lat_bf, w_kvb_bf, k_full, v_exp_t);
    // 10. flash attention (XCD-affine grid: x=bh, y=q-block)
    flash_mfma<<<dim3(BB * NH, SS / 128), dim3(512), 0, stream>>>(
        q_full, k_full, v_exp_t, attnv_bf);
    // 11. G7: out = attnv @ w_o^T -> fp32
    gemm_f32out<<<dim3(16, 32), blk, 0, stream>>>(
        attnv_bf, w_o_bf, out, NH * DV, NH * DV, NH * DV, D_MODEL);
}